// Round 11
// baseline (71.860 us; speedup 1.0000x reference)
//
#include <hip/hip_runtime.h>
#include <hip/hip_bf16.h>
#include <stdint.h>

#define EMBED  128
#define HIDDEN 512
#define TB     32    // tokens per mlp block
#define HHALF  256   // hidden cols per pass (2 passes)
#define CAP    32    // bucket capacity per vocab row (Poisson lambda=4; P(>32)~1e-19)

typedef __attribute__((ext_vector_type(8))) short short8v;   // 8 bf16 = 4 VGPR
typedef __attribute__((ext_vector_type(8))) ushort ushort8v;
typedef __attribute__((ext_vector_type(4))) float f32x4;

__device__ __forceinline__ ushort f2bf(float f) {
    uint32_t b = __float_as_uint(f);
    uint32_t r = (b + 0x7FFFu + ((b >> 16) & 1u)) >> 16;
    return (ushort)r;
}
__device__ __forceinline__ float bf2f(ushort u) {
    return __uint_as_float(((uint32_t)u) << 16);
}

__device__ __forceinline__ float gelu_fast(float x) {
    // 0.5x(1+tanh(u)) == x - x/(exp(2u)+1),  u = 0.79788456(x + 0.044715x^3)
    float x2 = x * x;
    float u  = x * fmaf(0.035677408136f, x2, 0.7978845608f);
    float t  = __expf(2.0f * u);
    return x - x * __frcp_rn(t + 1.0f);
}

// ---------------------------------------------------------------------------
// K1: blocks [0,128)           : weight transpose + bf16 cast
//     blocks [128,128+zb)      : zero cnt
//     blocks [128+zb, ...)     : table fp32 -> bf16 (tbf)
// ---------------------------------------------------------------------------
__global__ __launch_bounds__(256)
void prep_kernel(const float* __restrict__ w1, const float* __restrict__ w2,
                 ushort* __restrict__ W1t, ushort* __restrict__ W2t,
                 int* __restrict__ cnt, int vocab,
                 const float* __restrict__ table, ushort* __restrict__ tbf,
                 int zb, int n8) {
    __shared__ float T[32][33];
    int b = blockIdx.x;
    int t = threadIdx.x;
    if (b < 128) {
        const float* in; ushort* outp; int inCols, outCols, tr, tc;
        if (b < 64) {            // W1: [128][512] -> W1t [512][128]
            in = w1; outp = W1t; inCols = 512; outCols = 128;
            tr = b >> 4; tc = b & 15;
        } else {                 // W2: [512][128] -> W2t [128][512]
            int b2 = b - 64;
            in = w2; outp = W2t; inCols = 128; outCols = 512;
            tr = b2 >> 2; tc = b2 & 3;
        }
        int r  = t >> 3;
        int c4 = (t & 7) * 4;
        float4 v = *(const float4*)&in[(size_t)(tr * 32 + r) * inCols + tc * 32 + c4];
        T[c4 + 0][r] = v.x; T[c4 + 1][r] = v.y; T[c4 + 2][r] = v.z; T[c4 + 3][r] = v.w;
        __syncthreads();
        ushort o[4];
        #pragma unroll
        for (int i = 0; i < 4; ++i) o[i] = f2bf(T[r][c4 + i]);
        *(ushort4*)&outp[(size_t)(tc * 32 + r) * outCols + tr * 32 + c4] = *(ushort4*)o;
    } else if (b < 128 + zb) {
        int i = (b - 128) * 256 + t;
        if (i < vocab) cnt[i] = 0;
    } else {
        int gid = (b - 128 - zb) * 256 + t;      // one 8-elem granule per thread
        if (gid < n8) {
            const float* src = table + (size_t)gid * 8;
            float4 v0 = *(const float4*)(src);
            float4 v1 = *(const float4*)(src + 4);
            ushort u[8] = {f2bf(v0.x), f2bf(v0.y), f2bf(v0.z), f2bf(v0.w),
                           f2bf(v1.x), f2bf(v1.y), f2bf(v1.z), f2bf(v1.w)};
            *(short8v*)&tbf[(size_t)gid * 8] = *(short8v*)u;
        }
    }
}

// ---------------------------------------------------------------------------
// K2: bucket ALL bloom entries into CSR (ushort entries: vocab < 65536)
// ---------------------------------------------------------------------------
__global__ __launch_bounds__(256)
void bucket_kernel(const int* __restrict__ bi, const int* __restrict__ bj,
                   int* __restrict__ cnt, ushort* __restrict__ csr, int nk) {
    int k = blockIdx.x * blockDim.x + threadIdx.x;
    if (k >= nk) return;
    int i = bi[k];
    int slot = atomicAdd(&cnt[i], 1);
    if (slot < CAP) csr[(size_t)i * CAP + slot] = (ushort)bj[k];
}

// ---------------------------------------------------------------------------
// K3: fused bloom-gather + bf16-MFMA MLP, hidden in 2 halves.
// TB=32 tokens, 512 threads = 8 waves, 1024 blocks, LDS 24 KB.
// __launch_bounds__(512,6): <=85 VGPR -> 3 blocks/CU (24 waves) WITHOUT spills.
// Gather: 16 threads/token; indices via one ushort8 load; 8 row-loads
// issued into regs before any consume (explicit MLP).
// ---------------------------------------------------------------------------
__global__ __launch_bounds__(512, 6)
void mlp_mfma_kernel(const int*    __restrict__ tokens,
                     const ushort* __restrict__ tbf,   // [vocab][128] bf16
                     const int*    __restrict__ cnt,
                     const ushort* __restrict__ csr,
                     const ushort* __restrict__ W1t,   // [512][128] bf16
                     const ushort* __restrict__ W2t,   // [128][512] bf16
                     const float*  __restrict__ b1,
                     const float*  __restrict__ b2,
                     float*        __restrict__ out) {
    __shared__ ushort Xs[TB * EMBED];    // 8 KB, XOR-swizzled (granule16 ^= row&7)
    __shared__ ushort Hs[TB * HHALF];    // 16 KB, XOR-swizzled

    const int t    = threadIdx.x;
    const int lane = t & 63;
    const int wv   = t >> 6;             // 0..7
    const int base = blockIdx.x * TB;
    const int l15  = lane & 15;
    const int lhi  = lane >> 4;          // 0..3

    // ---- X-stage: inline bloom aggregation, 16 threads/token ----
    {
        int r   = t >> 4;                // 0..31 token row
        int c8  = t & 15;                // granule (8 bf16 cols)
        int tok = tokens[base + r];
        int m   = min(cnt[tok], CAP);
        const ushort* jrow = csr + (size_t)tok * CAP;
        ushort8v jv = *(const ushort8v*)jrow;       // 8 indices, one 16B load

        // issue all 8 row loads before consuming (MLP)
        short8v v[8];
        #pragma unroll
        for (int e = 0; e < 8; ++e) {
            int j = (e < m) ? (int)jv[e] : 0;
            v[e] = *(const short8v*)&tbf[(size_t)j * EMBED + c8 * 8];
        }
        float acc[8] = {0.f,0.f,0.f,0.f,0.f,0.f,0.f,0.f};
        #pragma unroll
        for (int e = 0; e < 8; ++e) {
            if (e < m) {
                #pragma unroll
                for (int q = 0; q < 8; ++q) acc[q] += bf2f((ushort)v[e][q]);
            }
        }
        for (int e = 8; e < m; ++e) {    // rare tail (P ~2%)
            int j = (int)jrow[e];
            short8v w = *(const short8v*)&tbf[(size_t)j * EMBED + c8 * 8];
            #pragma unroll
            for (int q = 0; q < 8; ++q) acc[q] += bf2f((ushort)w[q]);
        }
        ushort u[8];
        #pragma unroll
        for (int q = 0; q < 8; ++q) u[q] = f2bf(0.5f * acc[q]);
        *(short8v*)&Xs[r * EMBED + (c8 ^ (r & 7)) * 8] = *(short8v*)u;
    }
    __syncthreads();

    // ---- out accumulator persists across both hidden halves ----
    f32x4 acc2[2];
    {
        float bv = b2[wv * 16 + l15];
        acc2[0] = (f32x4){bv, bv, bv, bv};
        acc2[1] = acc2[0];
    }

    #pragma unroll
    for (int h = 0; h < 2; ++h) {
        // ---- GEMM1 half: H[32][32 per wave] = X @ W1[:, h*256+wv*32 ...] ----
        f32x4 acc1[2][2];
        #pragma unroll
        for (int n = 0; n < 2; ++n) {
            float bv = b1[h * HHALF + wv * 32 + n * 16 + l15];
            acc1[0][n] = (f32x4){bv, bv, bv, bv};
            acc1[1][n] = acc1[0][n];
        }
        #pragma unroll
        for (int kk = 0; kk < EMBED / 32; ++kk) {   // 4 k-steps
            short8v a[2];
            #pragma unroll
            for (int m = 0; m < 2; ++m) {
                int r = m * 16 + l15;
                int g = (kk * 4 + lhi) ^ (r & 7);
                a[m] = *(const short8v*)&Xs[r * EMBED + g * 8];
            }
            #pragma unroll
            for (int n = 0; n < 2; ++n) {
                int col = h * HHALF + wv * 32 + n * 16 + l15;
                short8v b = *(const short8v*)(W1t + (size_t)col * EMBED + kk * 32 + lhi * 8);
                #pragma unroll
                for (int m = 0; m < 2; ++m)
                    acc1[m][n] = __builtin_amdgcn_mfma_f32_16x16x32_bf16(a[m], b, acc1[m][n], 0, 0, 0);
            }
        }

        // ---- gelu -> bf16 -> swizzled Hs (cols within half: 0..255) ----
        #pragma unroll
        for (int n = 0; n < 2; ++n) {
            int colh = wv * 32 + n * 16 + l15;
            #pragma unroll
            for (int m = 0; m < 2; ++m)
                #pragma unroll
                for (int q = 0; q < 4; ++q) {
                    int row = m * 16 + lhi * 4 + q;
                    float hv = gelu_fast(acc1[m][n][q]);
                    int g = (colh >> 3) ^ (row & 7);
                    Hs[row * HHALF + g * 8 + (colh & 7)] = f2bf(hv);
                }
        }
        __syncthreads();

        // ---- GEMM2 half: acc2 += H_half @ W2[h*256 ...] ----
        #pragma unroll
        for (int kk = 0; kk < HHALF / 32; ++kk) {   // 8 k-steps
            short8v a[2];
            #pragma unroll
            for (int m = 0; m < 2; ++m) {
                int r = m * 16 + l15;
                int g = (kk * 4 + lhi) ^ (r & 7);
                a[m] = *(const short8v*)&Hs[r * HHALF + g * 8];
            }
            int col = wv * 16 + l15;
            short8v b = *(const short8v*)(W2t + (size_t)col * HIDDEN + h * HHALF + kk * 32 + lhi * 8);
            #pragma unroll
            for (int m = 0; m < 2; ++m)
                acc2[m] = __builtin_amdgcn_mfma_f32_16x16x32_bf16(a[m], b, acc2[m], 0, 0, 0);
        }
        __syncthreads();    // before next half overwrites Hs
    }

    // ---- store ----
    #pragma unroll
    for (int m = 0; m < 2; ++m)
        #pragma unroll
        for (int q = 0; q < 4; ++q) {
            int row = m * 16 + lhi * 4 + q;
            out[(size_t)(base + row) * EMBED + wv * 16 + l15] = acc2[m][q];
        }
}

// ---------------------------------------------------------------------------
extern "C" void kernel_launch(void* const* d_in, const int* in_sizes, int n_in,
                              void* d_out, int out_size, void* d_ws, size_t ws_size,
                              hipStream_t stream) {
    const int*   tokens = (const int*)  d_in[0];
    const float* table  = (const float*)d_in[1];
    const int*   bi     = (const int*)  d_in[2];
    const int*   bj     = (const int*)  d_in[3];
    const float* w1     = (const float*)d_in[4];
    const float* b1     = (const float*)d_in[5];
    const float* w2     = (const float*)d_in[6];
    const float* b2     = (const float*)d_in[7];
    float* out = (float*)d_out;

    const int vocab = in_sizes[1] / EMBED;   // 50257
    const int nk    = in_sizes[2];           // 4 * vocab
    const int ntok  = in_sizes[0];           // 32768

    // ---- workspace layout (~17 MB) ----
    char* ws = (char*)d_ws;
    size_t off = 0;
    auto alloc = [&](size_t b) { size_t o = off; off += (b + 255) & ~(size_t)255; return o; };
    ushort* W1t = (ushort*)(ws + alloc((size_t)EMBED * HIDDEN * 2));
    ushort* W2t = (ushort*)(ws + alloc((size_t)EMBED * HIDDEN * 2));
    ushort* tbf = (ushort*)(ws + alloc((size_t)vocab * EMBED * 2));
    ushort* csr = (ushort*)(ws + alloc((size_t)vocab * CAP * 2));
    int*    cnt = (int*)   (ws + alloc((size_t)vocab * 4));

    int zb = (vocab + 255) / 256;                        // 197 cnt-zero blocks
    int n8 = vocab * EMBED / 8;                          // 804112 table granules
    int cb = (n8 + 255) / 256;                           // 3142 convert blocks
    prep_kernel<<<128 + zb + cb, 256, 0, stream>>>(w1, w2, W1t, W2t, cnt, vocab,
                                                   table, tbf, zb, n8);

    bucket_kernel<<<(nk + 255) / 256, 256, 0, stream>>>(bi, bj, cnt, csr, nk);

    mlp_mfma_kernel<<<ntok / TB, 512, 0, stream>>>(tokens, tbf, cnt, csr,
                                                   W1t, W2t, b1, b2, out);
}

// Round 12
// 58.474 us; speedup vs baseline: 1.2289x; 1.2289x over previous
//
#include <hip/hip_runtime.h>
#include <hip/hip_bf16.h>
#include <stdint.h>

#define EMBED  128
#define HIDDEN 512
#define TB     64    // tokens per mlp block
#define HHALF  256   // hidden cols per pass (2 passes)
#define CAP    32    // bucket capacity per vocab row (Poisson lambda=4; P(>32)~1e-19)

typedef __attribute__((ext_vector_type(8))) short short8v;   // 8 bf16 = 4 VGPR
typedef __attribute__((ext_vector_type(8))) ushort ushort8v;
typedef __attribute__((ext_vector_type(4))) float f32x4;

__device__ __forceinline__ ushort f2bf(float f) {
    uint32_t b = __float_as_uint(f);
    uint32_t r = (b + 0x7FFFu + ((b >> 16) & 1u)) >> 16;
    return (ushort)r;
}
__device__ __forceinline__ float bf2f(ushort u) {
    return __uint_as_float(((uint32_t)u) << 16);
}

__device__ __forceinline__ float gelu_fast(float x) {
    // 0.5x(1+tanh(u)) == x - x/(exp(2u)+1),  u = 0.79788456(x + 0.044715x^3)
    float x2 = x * x;
    float u  = x * fmaf(0.035677408136f, x2, 0.7978845608f);
    float t  = __expf(2.0f * u);
    return x - x * __frcp_rn(t + 1.0f);
}

// ---------------------------------------------------------------------------
// K1: zero cnt (must precede bucket)
// ---------------------------------------------------------------------------
__global__ void zero_kernel(int* __restrict__ p, int n) {
    int i = blockIdx.x * blockDim.x + threadIdx.x;
    if (i < n) p[i] = 0;
}

// ---------------------------------------------------------------------------
// K2: independent roles by blockIdx:
//   [0,128)           : weight transpose + bf16 cast
//   [128,128+cb)      : table fp32 -> bf16 (tbf)
//   [128+cb, ...)     : bucket bloom entries into CSR (ushort)
// ---------------------------------------------------------------------------
__global__ __launch_bounds__(256)
void prep_kernel(const float* __restrict__ w1, const float* __restrict__ w2,
                 ushort* __restrict__ W1t, ushort* __restrict__ W2t,
                 const float* __restrict__ table, ushort* __restrict__ tbf, int n8, int cb,
                 const int* __restrict__ bi, const int* __restrict__ bj, int nk,
                 int* __restrict__ cnt, ushort* __restrict__ csr) {
    __shared__ float T[32][33];
    int b = blockIdx.x;
    int t = threadIdx.x;
    if (b < 128) {
        const float* in; ushort* outp; int inCols, outCols, tr, tc;
        if (b < 64) {            // W1: [128][512] -> W1t [512][128]
            in = w1; outp = W1t; inCols = 512; outCols = 128;
            tr = b >> 4; tc = b & 15;
        } else {                 // W2: [512][128] -> W2t [128][512]
            int b2 = b - 64;
            in = w2; outp = W2t; inCols = 128; outCols = 512;
            tr = b2 >> 2; tc = b2 & 3;
        }
        int r  = t >> 3;
        int c4 = (t & 7) * 4;
        float4 v = *(const float4*)&in[(size_t)(tr * 32 + r) * inCols + tc * 32 + c4];
        T[c4 + 0][r] = v.x; T[c4 + 1][r] = v.y; T[c4 + 2][r] = v.z; T[c4 + 3][r] = v.w;
        __syncthreads();
        ushort o[4];
        #pragma unroll
        for (int i = 0; i < 4; ++i) o[i] = f2bf(T[r][c4 + i]);
        *(ushort4*)&outp[(size_t)(tc * 32 + r) * outCols + tr * 32 + c4] = *(ushort4*)o;
    } else if (b < 128 + cb) {
        int gid = (b - 128) * 256 + t;           // one 8-elem granule per thread
        if (gid < n8) {
            const float* src = table + (size_t)gid * 8;
            float4 v0 = *(const float4*)(src);
            float4 v1 = *(const float4*)(src + 4);
            ushort u[8] = {f2bf(v0.x), f2bf(v0.y), f2bf(v0.z), f2bf(v0.w),
                           f2bf(v1.x), f2bf(v1.y), f2bf(v1.z), f2bf(v1.w)};
            *(short8v*)&tbf[(size_t)gid * 8] = *(short8v*)u;
        }
    } else {
        int k = (b - 128 - cb) * 256 + t;
        if (k < nk) {
            int i = bi[k];
            int slot = atomicAdd(&cnt[i], 1);
            if (slot < CAP) csr[(size_t)i * CAP + slot] = (ushort)bj[k];
        }
    }
}

// ---------------------------------------------------------------------------
// K3: fused bloom-gather + bf16-MFMA MLP, hidden in 2 halves (R9 structure).
// TB=64 tokens, 512 threads = 8 waves, 512 blocks, LDS 48 KB.
// Gather: 8 threads/token, 2x16B bf16 loads per bloom row, all 16 issued
// before consumption (deep MLP; ~100 VGPR is free at 2 blk/CU).
// GEMM1 half: wave w -> hid cols [h*256+w*32, +32)   acc 4x2 f32x4
// GEMM2 half: wave w -> out cols [w*16, +16)          acc 4   f32x4 (persists)
// ---------------------------------------------------------------------------
__global__ __launch_bounds__(512)
void mlp_mfma_kernel(const int*    __restrict__ tokens,
                     const ushort* __restrict__ tbf,   // [vocab][128] bf16
                     const int*    __restrict__ cnt,
                     const ushort* __restrict__ csr,
                     const ushort* __restrict__ W1t,   // [512][128] bf16
                     const ushort* __restrict__ W2t,   // [128][512] bf16
                     const float*  __restrict__ b1,
                     const float*  __restrict__ b2,
                     float*        __restrict__ out) {
    __shared__ ushort Xs[TB * EMBED];    // 16 KB, XOR-swizzled (granule16 ^= row&7)
    __shared__ ushort Hs[TB * HHALF];    // 32 KB, XOR-swizzled

    const int t    = threadIdx.x;
    const int lane = t & 63;
    const int wv   = t >> 6;             // 0..7
    const int base = blockIdx.x * TB;
    const int l15  = lane & 15;
    const int lhi  = lane >> 4;          // 0..3

    // ---- X-stage: inline bloom aggregation, 8 threads/token x 16 bf16 cols ----
    {
        int r    = t >> 3;               // 0..63 token row
        int c16  = t & 7;                // 16-col segment (two 8-granules)
        int tok  = tokens[base + r];
        int m    = min(cnt[tok], CAP);
        const ushort* jrow = csr + (size_t)tok * CAP;
        ushort8v jv = *(const ushort8v*)jrow;       // 8 indices, one 16B load

        // issue all 16 row-segment loads before consuming (deep MLP)
        short8v v[8][2];
        #pragma unroll
        for (int e = 0; e < 8; ++e) {
            int j = (e < m) ? (int)jv[e] : 0;
            const ushort* trp = tbf + (size_t)j * EMBED + c16 * 16;
            v[e][0] = *(const short8v*)(trp);
            v[e][1] = *(const short8v*)(trp + 8);
        }
        float acc[16] = {0.f,0.f,0.f,0.f,0.f,0.f,0.f,0.f,
                         0.f,0.f,0.f,0.f,0.f,0.f,0.f,0.f};
        #pragma unroll
        for (int e = 0; e < 8; ++e) {
            if (e < m) {
                #pragma unroll
                for (int q = 0; q < 8; ++q) {
                    acc[q]     += bf2f((ushort)v[e][0][q]);
                    acc[8 + q] += bf2f((ushort)v[e][1][q]);
                }
            }
        }
        for (int e = 8; e < m; ++e) {    // rare tail (P ~2%)
            int j = (int)jrow[e];
            const ushort* trp = tbf + (size_t)j * EMBED + c16 * 16;
            short8v w0 = *(const short8v*)(trp);
            short8v w1 = *(const short8v*)(trp + 8);
            #pragma unroll
            for (int q = 0; q < 8; ++q) {
                acc[q]     += bf2f((ushort)w0[q]);
                acc[8 + q] += bf2f((ushort)w1[q]);
            }
        }
        ushort u[16];
        #pragma unroll
        for (int q = 0; q < 16; ++q) u[q] = f2bf(0.5f * acc[q]);
        int g0 = c16 * 2;
        #pragma unroll
        for (int h = 0; h < 2; ++h)
            *(short8v*)&Xs[r * EMBED + ((g0 + h) ^ (r & 7)) * 8] = *(short8v*)&u[h * 8];
    }
    __syncthreads();

    // ---- out accumulator persists across both hidden halves ----
    f32x4 acc2[4];
    {
        float bv = b2[wv * 16 + l15];
        #pragma unroll
        for (int m = 0; m < 4; ++m) acc2[m] = (f32x4){bv, bv, bv, bv};
    }

    #pragma unroll
    for (int h = 0; h < 2; ++h) {
        // ---- GEMM1 half: H[64][32 per wave] = X @ W1[:, h*256+wv*32 ...] ----
        f32x4 acc1[4][2];
        #pragma unroll
        for (int n = 0; n < 2; ++n) {
            float bv = b1[h * HHALF + wv * 32 + n * 16 + l15];
            #pragma unroll
            for (int m = 0; m < 4; ++m) acc1[m][n] = (f32x4){bv, bv, bv, bv};
        }
        #pragma unroll
        for (int kk = 0; kk < EMBED / 32; ++kk) {   // 4 k-steps
            short8v a[4];
            #pragma unroll
            for (int m = 0; m < 4; ++m) {
                int r = m * 16 + l15;
                int g = (kk * 4 + lhi) ^ (r & 7);
                a[m] = *(const short8v*)&Xs[r * EMBED + g * 8];
            }
            #pragma unroll
            for (int n = 0; n < 2; ++n) {
                int col = h * HHALF + wv * 32 + n * 16 + l15;
                short8v b = *(const short8v*)(W1t + (size_t)col * EMBED + kk * 32 + lhi * 8);
                #pragma unroll
                for (int m = 0; m < 4; ++m)
                    acc1[m][n] = __builtin_amdgcn_mfma_f32_16x16x32_bf16(a[m], b, acc1[m][n], 0, 0, 0);
            }
        }

        // ---- gelu -> bf16 -> swizzled Hs (cols within half: 0..255) ----
        #pragma unroll
        for (int n = 0; n < 2; ++n) {
            int colh = wv * 32 + n * 16 + l15;
            #pragma unroll
            for (int m = 0; m < 4; ++m)
                #pragma unroll
                for (int q = 0; q < 4; ++q) {
                    int row = m * 16 + lhi * 4 + q;
                    float hv = gelu_fast(acc1[m][n][q]);
                    int g = (colh >> 3) ^ (row & 7);
                    Hs[row * HHALF + g * 8 + (colh & 7)] = f2bf(hv);
                }
        }
        __syncthreads();

        // ---- GEMM2 half: acc2 += H_half @ W2[h*256 ...] ----
        #pragma unroll
        for (int kk = 0; kk < HHALF / 32; ++kk) {   // 8 k-steps
            short8v a[4];
            #pragma unroll
            for (int m = 0; m < 4; ++m) {
                int r = m * 16 + l15;
                int g = (kk * 4 + lhi) ^ (r & 7);
                a[m] = *(const short8v*)&Hs[r * HHALF + g * 8];
            }
            int col = wv * 16 + l15;
            short8v b = *(const short8v*)(W2t + (size_t)col * HIDDEN + h * HHALF + kk * 32 + lhi * 8);
            #pragma unroll
            for (int m = 0; m < 4; ++m)
                acc2[m] = __builtin_amdgcn_mfma_f32_16x16x32_bf16(a[m], b, acc2[m], 0, 0, 0);
        }
        __syncthreads();    // before next half overwrites Hs
    }

    // ---- store ----
    #pragma unroll
    for (int m = 0; m < 4; ++m)
        #pragma unroll
        for (int q = 0; q < 4; ++q) {
            int row = m * 16 + lhi * 4 + q;
            out[(size_t)(base + row) * EMBED + wv * 16 + l15] = acc2[m][q];
        }
}

// ---------------------------------------------------------------------------
extern "C" void kernel_launch(void* const* d_in, const int* in_sizes, int n_in,
                              void* d_out, int out_size, void* d_ws, size_t ws_size,
                              hipStream_t stream) {
    const int*   tokens = (const int*)  d_in[0];
    const float* table  = (const float*)d_in[1];
    const int*   bi     = (const int*)  d_in[2];
    const int*   bj     = (const int*)  d_in[3];
    const float* w1     = (const float*)d_in[4];
    const float* b1     = (const float*)d_in[5];
    const float* w2     = (const float*)d_in[6];
    const float* b2     = (const float*)d_in[7];
    float* out = (float*)d_out;

    const int vocab = in_sizes[1] / EMBED;   // 50257
    const int nk    = in_sizes[2];           // 4 * vocab
    const int ntok  = in_sizes[0];           // 32768

    // ---- workspace layout (~17 MB) ----
    char* ws = (char*)d_ws;
    size_t off = 0;
    auto alloc = [&](size_t b) { size_t o = off; off += (b + 255) & ~(size_t)255; return o; };
    ushort* W1t = (ushort*)(ws + alloc((size_t)EMBED * HIDDEN * 2));
    ushort* W2t = (ushort*)(ws + alloc((size_t)EMBED * HIDDEN * 2));
    ushort* tbf = (ushort*)(ws + alloc((size_t)vocab * EMBED * 2));
    ushort* csr = (ushort*)(ws + alloc((size_t)vocab * CAP * 2));
    int*    cnt = (int*)   (ws + alloc((size_t)vocab * 4));

    zero_kernel<<<(vocab + 255) / 256, 256, 0, stream>>>(cnt, vocab);

    int n8 = vocab * EMBED / 8;                          // 804112 table granules
    int cb = (n8 + 255) / 256;                           // 3142 convert blocks
    int bb = (nk + 255) / 256;                           // 786 bucket blocks
    prep_kernel<<<128 + cb + bb, 256, 0, stream>>>(w1, w2, W1t, W2t,
                                                   table, tbf, n8, cb,
                                                   bi, bj, nk, cnt, csr);

    mlp_mfma_kernel<<<ntok / TB, 512, 0, stream>>>(tokens, tbf, cnt, csr,
                                                   W1t, W2t, b1, b2, out);
}